// Round 3
// baseline (82.863 us; speedup 1.0000x reference)
//
#include <hip/hip_runtime.h>
#include <math.h>

#define N_OBJ   8192
#define N_FLOOR 8192
#define STEPS   100
#define DT      0.01f
#define GDT     (-9.8f * 0.01f)   /* fp32 constant-folded g*DT */
#define TWO_R   0.002f
#define EPS12   1e-12f
#define BIGF    3.4e38f

// ws layout (as unsigned int array ws_u):
//   [0 .. 8191]   : ~bits of per-particle min xy^2 distance (atomicMax form)
//   [8192..8193]  : u64 ~key, key = (kf<<32)|d2bits  (atomicMax form)
//   [8194]        : grid-barrier arrive counter (zeroed by kernel 1)
// Poison-tolerance: harness fills ws with 0xAA. 0xAAAAAAAA loses atomicMax to
// ~bits of any real d2 (~0xC8xxxxxx); the u64 poison decodes to
// kstar=0x55555555 > STEPS => "no contact" if no particle ever submits a key.

// ---- Kernel 1: min over floor of (x-fx)^2+(y-fy)^2, 4 obj pts / thread -----
__global__ __launch_bounds__(256) void floor_min_xy_k(
    const float* __restrict__ obj, const float* __restrict__ flr,
    unsigned int* __restrict__ ws_u) {
    __shared__ float2 sf[128];
    const int t = threadIdx.x;
    if (blockIdx.x == 0 && blockIdx.y == 0 && t == 0)
        atomicExch(&ws_u[N_OBJ + 2], 0u);   // zero barrier ctr for kernel 2
    const int jbase = blockIdx.y * 128;
    if (t < 128) {
        int j = jbase + t;
        sf[t] = make_float2(flr[3 * j], flr[3 * j + 1]);
    }
    __syncthreads();
    const int ib = blockIdx.x * 1024;
    float x[4], y[4], m[4];
    #pragma unroll
    for (int c = 0; c < 4; ++c) {
        int i = ib + t + c * 256;
        x[c] = obj[3 * i];
        y[c] = obj[3 * i + 1];
        m[c] = BIGF;
    }
    #pragma unroll 4
    for (int j = 0; j < 128; ++j) {
        const float fx = sf[j].x, fy = sf[j].y;
        #pragma unroll
        for (int c = 0; c < 4; ++c) {
            float dx = x[c] - fx;
            float dy = y[c] - fy;
            // match numpy/XLA non-contracted (dx^2 + dy^2)
            float d = __fadd_rn(__fmul_rn(dx, dx), __fmul_rn(dy, dy));
            m[c] = fminf(m[c], d);
        }
    }
    #pragma unroll
    for (int c = 0; c < 4; ++c)
        atomicMax(&ws_u[ib + t + c * 256], ~__float_as_uint(m[c]));
}

// ---- Kernel 2: contact scan + grid barrier + output, fused -----------------
__global__ __launch_bounds__(256) void contact_out_k(
    const float* __restrict__ obj, unsigned int* __restrict__ ws_u,
    float* __restrict__ out) {
    __shared__ unsigned long long wkey[4];
    const int i = blockIdx.x * 256 + threadIdx.x;     // 32 blocks x 256 = 8192
    const float x = obj[3 * i], y = obj[3 * i + 1], z = obj[3 * i + 2];
    const float dxy2 = __uint_as_float(~ws_u[i]);

    // per-particle first ballistic contact step -> lex key (kf, d2bits)
    float v = 0.f, t = 0.f;
    unsigned long long key = ~0ull;
    for (int k = 1; k <= STEPS; ++k) {
        v = __fadd_rn(v, GDT);
        t = __fadd_rn(t, __fmul_rn(v, DT));
        float dz = __fadd_rn(z, t);
        float d2 = __fadd_rn(dxy2, __fmul_rn(dz, dz));
        float dmin = sqrtf(__fadd_rn(d2, EPS12));
        if (dmin < TWO_R) {
            key = ((unsigned long long)k << 32) | (unsigned long long)__float_as_uint(d2);
            break;
        }
    }
    // wave reduce, then block reduce, then one atomic per block
    #pragma unroll
    for (int off = 32; off; off >>= 1) {
        unsigned long long o = __shfl_down(key, off, 64);
        key = (o < key) ? o : key;
    }
    const int wv = threadIdx.x >> 6;
    if ((threadIdx.x & 63) == 0) wkey[wv] = key;
    __syncthreads();
    unsigned long long* key64 = (unsigned long long*)&ws_u[N_OBJ];
    unsigned int* ctr = &ws_u[N_OBJ + 2];
    if (threadIdx.x == 0) {
        unsigned long long bk = wkey[0];
        #pragma unroll
        for (int w = 1; w < 4; ++w) bk = (wkey[w] < bk) ? wkey[w] : bk;
        atomicMax(key64, ~bk);
        // arrive (release) + spin until all 32 blocks arrived
        __hip_atomic_fetch_add(ctr, 1u, __ATOMIC_ACQ_REL, __HIP_MEMORY_SCOPE_AGENT);
        while (__hip_atomic_load(ctr, __ATOMIC_ACQUIRE, __HIP_MEMORY_SCOPE_AGENT) < 32u)
            __builtin_amdgcn_s_sleep(8);
    }
    __syncthreads();   // holds the block until thread 0 clears the barrier

    const unsigned long long gkey =
        ~__hip_atomic_load(key64, __ATOMIC_RELAXED, __HIP_MEMORY_SCOPE_AGENT);
    const unsigned int kstar = (unsigned int)(gkey >> 32);
    float outz = z;
    float mask = 0.f;
    if (kstar <= STEPS) {
        float vv = 0.f, tt = 0.f;
        for (unsigned int k = 1; k <= kstar; ++k) {
            vv = __fadd_rn(vv, GDT);
            tt = __fadd_rn(tt, __fmul_rn(vv, DT));
        }
        const float d2min = __uint_as_float((unsigned int)(gkey & 0xFFFFFFFFu));
        const float dminmin = sqrtf(__fadd_rn(d2min, EPS12));
        const float maxpen = __fsub_rn(TWO_R, dminmin);
        const float tc = __fadd_rn(tt, maxpen);
        const float dz = __fadd_rn(z, tt);
        const float d2 = __fadd_rn(dxy2, __fmul_rn(dz, dz));
        const float dmin = sqrtf(__fadd_rn(d2, EPS12));
        if (dmin < TWO_R) {
            outz = __fadd_rn(z, tc);
            mask = 1.f;
        }
    }
    out[3 * i]     = x;
    out[3 * i + 1] = y;
    out[3 * i + 2] = outz;
    out[3 * N_OBJ + i] = mask;
}

extern "C" void kernel_launch(void* const* d_in, const int* in_sizes, int n_in,
                              void* d_out, int out_size, void* d_ws, size_t ws_size,
                              hipStream_t stream) {
    const float* obj = (const float*)d_in[0];   // [8192,3] f32
    const float* flr = (const float*)d_in[1];   // [8192,3] f32
    unsigned int* ws_u = (unsigned int*)d_ws;
    float* out = (float*)d_out;                 // 24576 + 8192 f32

    floor_min_xy_k<<<dim3(8, 64), dim3(256), 0, stream>>>(obj, flr, ws_u);
    contact_out_k<<<dim3(32), dim3(256), 0, stream>>>(obj, ws_u, out);
}